// Round 9
// baseline (262.050 us; speedup 1.0000x reference)
//
#include <hip/hip_runtime.h>
#include <cstdint>
#include <cstddef>
#include <cmath>

// ---------------------------------------------------------------------------
// GCN: 3 layers. CSR (by dst) built once, then:
//   G1:  x @ W1 -> hf (bf16 MFMA)
//   F1:  agg(hf,+b1,relu) -> LDS A-tile -> @W2 -> hg        (fused, R9)
//   a2:  agg(hg,+b2,relu) -> hb
//   F2:  agg(hb)          -> LDS A-tile -> @W3 +b3 +lsm -> out (fused, R9)
// R7: 2-level bucket-sort CSR (single-XCD-owned scatter regions).
// R8 learned: agg gather is below-L2-BW bound at its byte floor (each XCD
//   fetches each h row once, ~84 MB). R9 removes the remaining STREAMING
//   traffic: agg results go straight into the GEMM A-tile in LDS, killing
//   2x(12.8 MB write + 12.8 MB read) and 2 dispatches.
// ---------------------------------------------------------------------------

typedef __attribute__((ext_vector_type(8))) short short8;
typedef __attribute__((ext_vector_type(4))) float f32x4;

constexpr int EPB = 4096;  // edges per workgroup in bucket hist/scatter

__device__ __forceinline__ ushort f2bf(float f) {
  union { float f; uint32_t u; } x; x.f = f;
  uint32_t r = x.u + 0x7fffu + ((x.u >> 16) & 1u);  // RNE
  return (ushort)(r >> 16);
}
__device__ __forceinline__ float bf2f(ushort u) {
  union { uint32_t u; float f; } x; x.u = ((uint32_t)u) << 16;
  return x.f;
}

// ---------------- CSR build: 2-level bucket sort ----------------
__global__ __launch_bounds__(256) void bucket_hist_kernel(const int* __restrict__ dst,
                                                          int* __restrict__ bucket_count,
                                                          int E) {
  __shared__ int h[256];
  const int t  = threadIdx.x;
  const int e0 = blockIdx.x * EPB;
  const int myE = min(EPB, E - e0);
  h[t] = 0;
  __syncthreads();
  for (int i = t; i < myE; i += 256) atomicAdd(&h[dst[e0 + i] >> 8], 1);
  __syncthreads();
  if (h[t]) atomicAdd(&bucket_count[t], h[t]);
}

__global__ __launch_bounds__(256) void bucket_scan_kernel(const int* __restrict__ bucket_count,
                                                          int* __restrict__ bucket_offs,
                                                          int* __restrict__ bucket_cursor,
                                                          int* __restrict__ offs,
                                                          int nbuck, int n) {
  __shared__ int s[256];
  const int t = threadIdx.x;
  const int c = (t < nbuck) ? bucket_count[t] : 0;
  s[t] = c;
  __syncthreads();
  for (int off = 1; off < 256; off <<= 1) {
    int v = (t >= off) ? s[t - off] : 0;
    __syncthreads();
    s[t] += v;
    __syncthreads();
  }
  if (t < nbuck) {
    bucket_offs[t]   = s[t] - c;
    bucket_cursor[t] = s[t] - c;
  }
  if (t == 255) {
    bucket_offs[nbuck] = s[255];
    offs[n] = s[255];
  }
}

__global__ __launch_bounds__(256) void bucket_scatter_kernel(const int* __restrict__ src,
                                                             const int* __restrict__ dst,
                                                             int* __restrict__ bucket_cursor,
                                                             int2* __restrict__ staged,
                                                             int E, int nbuck) {
  __shared__ int hist[256], s[256], lstart[256], cbase[256], lcur[256];
  __shared__ int2 stage[EPB];  // 32 KB
  const int t  = threadIdx.x;
  const int e0 = blockIdx.x * EPB;
  const int myE = min(EPB, E - e0);
  hist[t] = 0;
  __syncthreads();
  for (int i = t; i < myE; i += 256) atomicAdd(&hist[dst[e0 + i] >> 8], 1);
  __syncthreads();
  const int c = hist[t];
  s[t] = c;
  __syncthreads();
  for (int off = 1; off < 256; off <<= 1) {
    int v = (t >= off) ? s[t - off] : 0;
    __syncthreads();
    s[t] += v;
    __syncthreads();
  }
  lstart[t] = s[t] - c;
  lcur[t]   = s[t] - c;
  cbase[t]  = (c > 0 && t < nbuck) ? atomicAdd(&bucket_cursor[t], c) : 0;
  __syncthreads();
  for (int i = t; i < myE; i += 256) {
    const int sv = src[e0 + i], dv = dst[e0 + i];
    const int slot = atomicAdd(&lcur[dv >> 8], 1);
    stage[slot] = make_int2(sv, dv);
  }
  __syncthreads();
  for (int i = t; i < myE; i += 256) {
    const int2 sd = stage[i];
    const int b = sd.y >> 8;
    staged[cbase[b] + (i - lstart[b])] = sd;
  }
}

__global__ __launch_bounds__(256) void bucket_csr_kernel(const int2* __restrict__ staged,
                                                         const int* __restrict__ bucket_offs,
                                                         int* __restrict__ offs,
                                                         float* __restrict__ dinv, int n) {
  __shared__ int cnt[256], s[256];
  const int t = threadIdx.x, b = blockIdx.x;
  cnt[t] = 0;
  __syncthreads();
  const int ebeg = bucket_offs[b], eend = bucket_offs[b + 1];
  for (int i = ebeg + t; i < eend; i += 256) atomicAdd(&cnt[staged[i].y & 255], 1);
  __syncthreads();
  const int c = cnt[t];
  s[t] = c;
  __syncthreads();
  for (int off = 1; off < 256; off <<= 1) {
    int v = (t >= off) ? s[t - off] : 0;
    __syncthreads();
    s[t] += v;
    __syncthreads();
  }
  const int node = (b << 8) + t;
  if (node < n) {
    offs[node] = ebeg + s[t] - c;
    dinv[node] = rsqrtf((float)(c + 1));  // +1 self-loop
  }
}

__global__ __launch_bounds__(256) void bucket_fill_kernel(const int2* __restrict__ staged,
                                                          const int* __restrict__ bucket_offs,
                                                          const float* __restrict__ dinv,
                                                          int2* __restrict__ epair, int n) {
  __shared__ int cnt[256], s[256], cur[256];
  const int t = threadIdx.x, b = blockIdx.x;
  cnt[t] = 0;
  __syncthreads();
  const int ebeg = bucket_offs[b], eend = bucket_offs[b + 1];
  for (int i = ebeg + t; i < eend; i += 256) atomicAdd(&cnt[staged[i].y & 255], 1);
  __syncthreads();
  const int c = cnt[t];
  s[t] = c;
  __syncthreads();
  for (int off = 1; off < 256; off <<= 1) {
    int v = (t >= off) ? s[t - off] : 0;
    __syncthreads();
    s[t] += v;
    __syncthreads();
  }
  cur[t] = ebeg + s[t] - c;
  __syncthreads();
  for (int i = ebeg + t; i < eend; i += 256) {
    const int2 sd = staged[i];
    const int pos = atomicAdd(&cur[sd.y & 255], 1);
    epair[pos] = make_int2(sd.x, __float_as_int(dinv[sd.x] * dinv[sd.y]));
  }
}

// ---------------- W pre-pack into MFMA B-fragment order ----------------
__global__ __launch_bounds__(256) void pack_w_kernel(const float* __restrict__ W,
                                                     ushort* __restrict__ Wp,
                                                     int K, int N, int NF) {
  const int idx  = blockIdx.x * blockDim.x + threadIdx.x;
  const int lane = idx & 63;
  const int nf   = (idx >> 6) % NF;
  const int g    = idx / (64 * NF);
  if (g * 32 >= K) return;
  const int n  = nf * 16 + (lane & 15);
  const int kb = g * 32 + (lane >> 4) * 8;
  ushort v[8];
#pragma unroll
  for (int j = 0; j < 8; ++j) {
    const float f = (n < N) ? W[(size_t)(kb + j) * N + n] : 0.f;
    v[j] = f2bf(f);
  }
  *(short8*)&Wp[((size_t)(g * NF + nf) * 64 + lane) * 8] = *(short8*)v;
}

// ---------------- MFMA GEMM: C[M,N] = A[M,K] @ W[K,N], bf16 out ----------------
template <int NF, bool AF32>
__global__ __launch_bounds__(256) void mfma_gemm_kernel(const void* __restrict__ Av,
                                                        const ushort* __restrict__ Wp,
                                                        ushort* __restrict__ C,
                                                        int M, int N, int K) {
  __shared__ ushort Atile[64 * 64];
  const int tid  = threadIdx.x;
  const int lane = tid & 63;
  const int wave = tid >> 6;
  const int brow = blockIdx.x * 64;

  f32x4 acc[NF];
#pragma unroll
  for (int nf = 0; nf < NF; ++nf) acc[nf] = (f32x4){0.f, 0.f, 0.f, 0.f};

  const int arow = wave * 16 + (lane & 15);
  const int ahi  = lane >> 4;
  const int row0 = tid >> 3;
  const int kc0  = tid & 7;

  for (int k0 = 0; k0 < K; k0 += 64) {
    if (k0) __syncthreads();
#pragma unroll
    for (int c = 0; c < 2; ++c) {
      const int row = row0 + c * 32;
      const int gr  = brow + row;
      short8 v = (short8){0, 0, 0, 0, 0, 0, 0, 0};
      if (gr < M) {
        if constexpr (AF32) {
          const float* A = (const float*)Av + (size_t)gr * K + k0 + kc0 * 8;
          const float4 f0 = *(const float4*)A;
          const float4 f1 = *(const float4*)(A + 4);
          v[0] = (short)f2bf(f0.x); v[1] = (short)f2bf(f0.y);
          v[2] = (short)f2bf(f0.z); v[3] = (short)f2bf(f0.w);
          v[4] = (short)f2bf(f1.x); v[5] = (short)f2bf(f1.y);
          v[6] = (short)f2bf(f1.z); v[7] = (short)f2bf(f1.w);
        } else {
          v = *(const short8*)((const ushort*)Av + (size_t)gr * K + k0 + kc0 * 8);
        }
      }
      *(short8*)&Atile[row * 64 + ((kc0 ^ (row & 7)) * 8)] = v;
    }
    __syncthreads();

    const int gbase = (k0 >> 5) * NF;
#pragma unroll
    for (int kk = 0; kk < 2; ++kk) {
      const int kc = kk * 4 + ahi;
      const short8 a =
          *(const short8*)&Atile[arow * 64 + ((kc ^ (arow & 7)) * 8)];
      const ushort* wp = Wp + ((size_t)(gbase + kk * NF) * 64 + lane) * 8;
#pragma unroll
      for (int nf = 0; nf < NF; ++nf) {
        const short8 b = *(const short8*)(wp + (size_t)nf * 64 * 8);
        acc[nf] = __builtin_amdgcn_mfma_f32_16x16x32_bf16(a, b, acc[nf], 0, 0, 0);
      }
    }
  }

  const int crow0 = brow + wave * 16 + (lane >> 4) * 4;
  const int ccol  = lane & 15;
#pragma unroll
  for (int nf = 0; nf < NF; ++nf) {
    const int col = nf * 16 + ccol;
    if (col < N) {
#pragma unroll
      for (int r = 0; r < 4; ++r) {
        const int row = crow0 + r;
        if (row < M) C[(size_t)row * N + col] = f2bf(acc[nf][r]);
      }
    }
  }
}

// ---------------- Fused agg -> GEMM (K fixed = 128) ----------------
// Phase 1: 4 waves aggregate 64 nodes (1 node/wave-iter, 4 edge-groups x
//          16 lanes x 8 feats, 2x unrolled) straight into swizzled LDS A-tiles.
// Phase 2: standard MFMA loop over the 2 K-tiles; bf16 store or lsm epilogue.
template <int NF, bool BIAS_RELU_AGG, bool LSM>
__global__ __launch_bounds__(256) void agg_gemm_kernel(
    const ushort* __restrict__ h, const int* __restrict__ offsets,
    const int2* __restrict__ epair, const float* __restrict__ dinv,
    const float* __restrict__ bias_agg, const ushort* __restrict__ Wp,
    const float* __restrict__ bias_out, void* __restrict__ Cv, int M, int N) {
  __shared__ ushort Atile[2][64 * 64];  // 16 KB, K=128 as two 64-k tiles
  const int tid  = threadIdx.x;
  const int lane = tid & 63;
  const int wave = tid >> 6;
  const int brow = blockIdx.x * 64;

  const int eg    = lane >> 4;        // edge group 0..3
  const int l15   = lane & 15;
  const int f0    = l15 * 8;          // features f0..f0+7
  const int ktile = l15 >> 3;         // which 64-k tile this lane's feats land in
  const int kca   = l15 & 7;          // k-chunk within tile

  // ---- phase 1: aggregation into LDS ----
  for (int i = 0; i < 16; ++i) {
    const int row  = wave * 16 + i;
    const int node = brow + row;
    float a8[8];
#pragma unroll
    for (int j = 0; j < 8; ++j) a8[j] = 0.f;
    if (node < M) {
      const int start = offsets[node];
      const int end   = offsets[node + 1];
      for (int eb = start; eb < end; eb += 8) {
        const int e0 = eb + eg;
        const int e1 = e0 + 4;
        if (e0 < end) {
          const int2  sw0 = epair[e0];
          const float w0  = __int_as_float(sw0.y);
          const short8 hv0 = *(const short8*)&h[(size_t)sw0.x * 128 + f0];
          if (e1 < end) {
            const int2  sw1 = epair[e1];
            const float w1  = __int_as_float(sw1.y);
            const short8 hv1 = *(const short8*)&h[(size_t)sw1.x * 128 + f0];
#pragma unroll
            for (int j = 0; j < 8; ++j) {
              a8[j] = fmaf(bf2f((ushort)hv0[j]), w0, a8[j]);
              a8[j] = fmaf(bf2f((ushort)hv1[j]), w1, a8[j]);
            }
          } else {
#pragma unroll
            for (int j = 0; j < 8; ++j) a8[j] = fmaf(bf2f((ushort)hv0[j]), w0, a8[j]);
          }
        }
      }
#pragma unroll
      for (int j = 0; j < 8; ++j) {
        a8[j] += __shfl_xor(a8[j], 16, 64);
        a8[j] += __shfl_xor(a8[j], 32, 64);
      }
    }
    if (eg == 0) {
      ushort o[8];
      if (node < M) {
        const float di  = dinv[node];
        const float di2 = di * di;
        const short8 hs = *(const short8*)&h[(size_t)node * 128 + f0];
#pragma unroll
        for (int j = 0; j < 8; ++j) {
          float a = fmaf(bf2f((ushort)hs[j]), di2, a8[j]);
          if (BIAS_RELU_AGG) a = fmaxf(a + bias_agg[f0 + j], 0.f);
          o[j] = f2bf(a);
        }
      } else {
#pragma unroll
        for (int j = 0; j < 8; ++j) o[j] = 0;  // zero tail rows
      }
      *(short8*)&Atile[ktile][row * 64 + ((kca ^ (row & 7)) << 3)] = *(short8*)o;
    }
  }
  __syncthreads();

  // ---- phase 2: MFMA over K=128 from LDS ----
  f32x4 acc[NF];
#pragma unroll
  for (int nf = 0; nf < NF; ++nf) acc[nf] = (f32x4){0.f, 0.f, 0.f, 0.f};
  const int arow = wave * 16 + (lane & 15);
  const int ahi  = lane >> 4;
#pragma unroll
  for (int kt = 0; kt < 2; ++kt) {
    const int gbase = kt * 2 * NF;
#pragma unroll
    for (int kk = 0; kk < 2; ++kk) {
      const int kc = kk * 4 + ahi;
      const short8 a =
          *(const short8*)&Atile[kt][arow * 64 + ((kc ^ (arow & 7)) * 8)];
      const ushort* wp = Wp + ((size_t)(gbase + kk * NF) * 64 + lane) * 8;
#pragma unroll
      for (int nf = 0; nf < NF; ++nf) {
        const short8 b = *(const short8*)(wp + (size_t)nf * 64 * 8);
        acc[nf] = __builtin_amdgcn_mfma_f32_16x16x32_bf16(a, b, acc[nf], 0, 0, 0);
      }
    }
  }

  // ---- epilogue ----
  const int ccol  = lane & 15;
  const int crow0 = brow + wave * 16 + (lane >> 4) * 4;
  if constexpr (!LSM) {
    ushort* C = (ushort*)Cv;
#pragma unroll
    for (int nf = 0; nf < NF; ++nf) {
      const int col = nf * 16 + ccol;
      if (col < N) {
#pragma unroll
        for (int r = 0; r < 4; ++r) {
          const int row = crow0 + r;
          if (row < M) C[(size_t)row * N + col] = f2bf(acc[nf][r]);
        }
      }
    }
  } else {
    float* out = (float*)Cv;
    float bv[NF];
#pragma unroll
    for (int nf = 0; nf < NF; ++nf) {
      const int col = nf * 16 + ccol;
      bv[nf] = (col < N) ? bias_out[col] : 0.f;
    }
    const bool v2ok = (32 + ccol) < N;
#pragma unroll
    for (int r = 0; r < 4; ++r) {
      const float v0 = acc[0][r] + bv[0];
      const float v1 = acc[1][r] + bv[1];
      const float v2 = acc[2][r] + bv[2];
      float m = fmaxf(v0, v1);
      if (v2ok) m = fmaxf(m, v2);
#pragma unroll
      for (int o = 8; o >= 1; o >>= 1) m = fmaxf(m, __shfl_xor(m, o, 64));
      float s = expf(v0 - m) + expf(v1 - m) + (v2ok ? expf(v2 - m) : 0.f);
#pragma unroll
      for (int o = 8; o >= 1; o >>= 1) s += __shfl_xor(s, o, 64);
      const float mls = m + logf(s);
      const int row = crow0 + r;
      if (row < M) {
        out[(size_t)row * N + ccol]      = v0 - mls;
        out[(size_t)row * N + 16 + ccol] = v1 - mls;
        if (v2ok) out[(size_t)row * N + 32 + ccol] = v2 - mls;
      }
    }
  }
}

// ---------------- Standalone aggregation (layer 2), unchanged from R8 ----------------
template <bool BIAS_RELU>
__global__ __launch_bounds__(256) void agg4_kernel(const ushort* __restrict__ h,
                                                   const int* __restrict__ offsets,
                                                   const int2* __restrict__ epair,
                                                   const float* __restrict__ dinv,
                                                   const float* __restrict__ bias,
                                                   ushort* __restrict__ out, int n) {
  const int wave = threadIdx.x >> 6;
  const int lane = threadIdx.x & 63;
  const int node = blockIdx.x * 4 + wave;
  if (node >= n) return;
  const int eg = lane >> 4;
  const int f0 = (lane & 15) * 8;

  float acc[8];
#pragma unroll
  for (int j = 0; j < 8; ++j) acc[j] = 0.f;

  const int start = offsets[node];
  const int end   = offsets[node + 1];
  for (int eb = start; eb < end; eb += 8) {
    const int e0 = eb + eg;
    const int e1 = e0 + 4;
    if (e0 < end) {
      const int2  sw0 = epair[e0];
      const float w0  = __int_as_float(sw0.y);
      const short8 hv0 = *(const short8*)&h[(size_t)sw0.x * 128 + f0];
      if (e1 < end) {
        const int2  sw1 = epair[e1];
        const float w1  = __int_as_float(sw1.y);
        const short8 hv1 = *(const short8*)&h[(size_t)sw1.x * 128 + f0];
#pragma unroll
        for (int j = 0; j < 8; ++j) {
          acc[j] = fmaf(bf2f((ushort)hv0[j]), w0, acc[j]);
          acc[j] = fmaf(bf2f((ushort)hv1[j]), w1, acc[j]);
        }
      } else {
#pragma unroll
        for (int j = 0; j < 8; ++j) acc[j] = fmaf(bf2f((ushort)hv0[j]), w0, acc[j]);
      }
    }
  }
#pragma unroll
  for (int j = 0; j < 8; ++j) {
    acc[j] += __shfl_xor(acc[j], 16, 64);
    acc[j] += __shfl_xor(acc[j], 32, 64);
  }
  if (eg == 0) {
    const float di  = dinv[node];
    const float di2 = di * di;
    const short8 hs = *(const short8*)&h[(size_t)node * 128 + f0];
    ushort o[8];
#pragma unroll
    for (int j = 0; j < 8; ++j) {
      float a = fmaf(bf2f((ushort)hs[j]), di2, acc[j]);
      if (BIAS_RELU) a = fmaxf(a + bias[f0 + j], 0.f);
      o[j] = f2bf(a);
    }
    *(short8*)&out[(size_t)node * 128 + f0] = *(short8*)o;
  }
}

extern "C" void kernel_launch(void* const* d_in, const int* in_sizes, int n_in,
                              void* d_out, int out_size, void* d_ws, size_t ws_size,
                              hipStream_t stream) {
  const float* x  = (const float*)d_in[0];
  const int*   ei = (const int*)d_in[1];
  const float* W1 = (const float*)d_in[2];
  const float* b1 = (const float*)d_in[3];
  const float* W2 = (const float*)d_in[4];
  const float* b2 = (const float*)d_in[5];
  const float* W3 = (const float*)d_in[6];
  const float* b3 = (const float*)d_in[7];

  const int h1   = in_sizes[3];        // 128
  const int h2   = in_sizes[5];        // 128
  const int ncls = in_sizes[7];        // 40
  const int fin  = in_sizes[2] / h1;   // 256
  const int n    = in_sizes[0] / fin;  // 50000
  const int E    = in_sizes[1] / 2;    // 800000

  const int* src = ei;
  const int* dst = ei + E;

  char* p = (char*)d_ws;
  auto alloc = [&](size_t bytes) {
    char* r = p;
    p += (bytes + 255) & ~size_t(255);
    return r;
  };
  float*  dinv   = (float*)alloc((size_t)n * 4);
  int*    offs   = (int*)alloc((size_t)(n + 1) * 4);
  int*    bcount = (int*)alloc(256 * 4);
  int*    boffs  = (int*)alloc(257 * 4);
  int*    bcur   = (int*)alloc(256 * 4);
  int2*   staged = (int2*)alloc((size_t)E * 8);
  int2*   epair  = (int2*)alloc((size_t)E * 8);
  ushort* hf     = (ushort*)alloc((size_t)n * h1 * 2);  // G1 out
  ushort* hg     = (ushort*)alloc((size_t)n * h1 * 2);  // F1 out
  ushort* hb     = hf;                                  // a2 out (hf dead after F1)
  ushort* Wp1    = (ushort*)alloc((size_t)(fin / 32) * 8 * 64 * 8 * 2);
  ushort* Wp2    = (ushort*)alloc((size_t)(h1 / 32) * 8 * 64 * 8 * 2);
  ushort* Wp3    = (ushort*)alloc((size_t)(h2 / 32) * 3 * 64 * 8 * 2);

  const int nbuck = (n + 255) >> 8;        // 196 (requires n <= 65536)
  const int ebw   = (E + EPB - 1) / EPB;   // 196 edge workgroups

  // --- CSR build: 2-level bucket sort ---
  hipMemsetAsync(bcount, 0, 256 * 4, stream);
  bucket_hist_kernel<<<ebw, 256, 0, stream>>>(dst, bcount, E);
  bucket_scan_kernel<<<1, 256, 0, stream>>>(bcount, boffs, bcur, offs, nbuck, n);
  bucket_scatter_kernel<<<ebw, 256, 0, stream>>>(src, dst, bcur, staged, E, nbuck);
  bucket_csr_kernel<<<nbuck, 256, 0, stream>>>(staged, boffs, offs, dinv, n);
  bucket_fill_kernel<<<nbuck, 256, 0, stream>>>(staged, boffs, dinv, epair, n);

  // --- pack weights (fragment order, bf16) ---
  {
    int t1 = (fin / 32) * 8 * 64;
    int t2 = (h1 / 32) * 8 * 64;
    int t3 = (h2 / 32) * 3 * 64;
    pack_w_kernel<<<(t1 + 255) / 256, 256, 0, stream>>>(W1, Wp1, fin, h1, 8);
    pack_w_kernel<<<(t2 + 255) / 256, 256, 0, stream>>>(W2, Wp2, h1, h2, 8);
    pack_w_kernel<<<(t3 + 255) / 256, 256, 0, stream>>>(W3, Wp3, h2, ncls, 3);
  }

  const int gblocks = (n + 63) / 64;
  const int ablocks = (n + 3) / 4;

  // --- G1: x @ W1 -> hf ---
  mfma_gemm_kernel<8, true><<<gblocks, 256, 0, stream>>>(x, Wp1, hf, n, h1, fin);
  // --- F1: agg(hf,+b1,relu) @ W2 -> hg (fused) ---
  agg_gemm_kernel<8, true, false><<<gblocks, 256, 0, stream>>>(
      hf, offs, epair, dinv, b1, Wp2, nullptr, hg, n, h2);
  // --- a2: agg(hg,+b2,relu) -> hb ---
  agg4_kernel<true><<<ablocks, 256, 0, stream>>>(hg, offs, epair, dinv, b2, hb, n);
  // --- F2: agg(hb) @ W3 +b3 +log_softmax -> out (fused) ---
  agg_gemm_kernel<3, false, true><<<gblocks, 256, 0, stream>>>(
      hb, offs, epair, dinv, nullptr, Wp3, b3, d_out, n, ncls);
}

// Round 10
// 237.681 us; speedup vs baseline: 1.1025x; 1.1025x over previous
//
#include <hip/hip_runtime.h>
#include <cstdint>
#include <cstddef>
#include <cmath>

// ---------------------------------------------------------------------------
// GCN: 3 layers. CSR (by dst) built once, then:
//   G1:  x @ W1 -> hf (bf16 MFMA)
//   F1': [agg(hf,+b1,relu) -> 16x128 LDS tile -> @W2] -> hg   (fused, R10)
//   a2:  agg(hg,+b2,relu) -> hf
//   F2': [agg(hf) -> 16x128 LDS tile -> @W3 +b3 +lsm] -> out  (fused, R10)
// R7: 2-level bucket-sort CSR. R8: agg gather = below-L2 byte floor (~84MB).
// R9 FAILED: 16 serial nodes/wave killed gather MLP (75us). R10 fuses with
//   16 waves/block, ONE node per wave (same 50000-wave geometry as agg4),
//   barrier, then 8 (or 3) waves do the tiny MFMA. Also packs CSR words:
//   staged = src|dst<<16, epair = src|bf16(norm)<<16  (requires n <= 65536).
// ---------------------------------------------------------------------------

typedef __attribute__((ext_vector_type(8))) short short8;
typedef __attribute__((ext_vector_type(4))) float f32x4;

constexpr int EPB = 4096;  // edges per workgroup in bucket hist/scatter

__device__ __forceinline__ ushort f2bf(float f) {
  union { float f; uint32_t u; } x; x.f = f;
  uint32_t r = x.u + 0x7fffu + ((x.u >> 16) & 1u);  // RNE
  return (ushort)(r >> 16);
}
__device__ __forceinline__ float bf2f(ushort u) {
  union { uint32_t u; float f; } x; x.u = ((uint32_t)u) << 16;
  return x.f;
}

// ---------------- CSR build: 2-level bucket sort ----------------
__global__ __launch_bounds__(256) void bucket_hist_kernel(const int* __restrict__ dst,
                                                          int* __restrict__ bucket_count,
                                                          int E) {
  __shared__ int h[256];
  const int t  = threadIdx.x;
  const int e0 = blockIdx.x * EPB;
  const int myE = min(EPB, E - e0);
  h[t] = 0;
  __syncthreads();
  for (int i = t; i < myE; i += 256) atomicAdd(&h[dst[e0 + i] >> 8], 1);
  __syncthreads();
  if (h[t]) atomicAdd(&bucket_count[t], h[t]);
}

__global__ __launch_bounds__(256) void bucket_scan_kernel(const int* __restrict__ bucket_count,
                                                          int* __restrict__ bucket_offs,
                                                          int* __restrict__ bucket_cursor,
                                                          int* __restrict__ offs,
                                                          int nbuck, int n) {
  __shared__ int s[256];
  const int t = threadIdx.x;
  const int c = (t < nbuck) ? bucket_count[t] : 0;
  s[t] = c;
  __syncthreads();
  for (int off = 1; off < 256; off <<= 1) {
    int v = (t >= off) ? s[t - off] : 0;
    __syncthreads();
    s[t] += v;
    __syncthreads();
  }
  if (t < nbuck) {
    bucket_offs[t]   = s[t] - c;
    bucket_cursor[t] = s[t] - c;
  }
  if (t == 255) {
    bucket_offs[nbuck] = s[255];
    offs[n] = s[255];
  }
}

// staged word = src | (dst << 16)   (src,dst < 65536)
__global__ __launch_bounds__(256) void bucket_scatter_kernel(const int* __restrict__ src,
                                                             const int* __restrict__ dst,
                                                             int* __restrict__ bucket_cursor,
                                                             uint32_t* __restrict__ staged,
                                                             int E, int nbuck) {
  __shared__ int hist[256], s[256], lstart[256], cbase[256], lcur[256];
  __shared__ uint32_t stage[EPB];  // 16 KB
  const int t  = threadIdx.x;
  const int e0 = blockIdx.x * EPB;
  const int myE = min(EPB, E - e0);
  hist[t] = 0;
  __syncthreads();
  for (int i = t; i < myE; i += 256) atomicAdd(&hist[dst[e0 + i] >> 8], 1);
  __syncthreads();
  const int c = hist[t];
  s[t] = c;
  __syncthreads();
  for (int off = 1; off < 256; off <<= 1) {
    int v = (t >= off) ? s[t - off] : 0;
    __syncthreads();
    s[t] += v;
    __syncthreads();
  }
  lstart[t] = s[t] - c;
  lcur[t]   = s[t] - c;
  cbase[t]  = (c > 0 && t < nbuck) ? atomicAdd(&bucket_cursor[t], c) : 0;
  __syncthreads();
  for (int i = t; i < myE; i += 256) {
    const int sv = src[e0 + i], dv = dst[e0 + i];
    const int slot = atomicAdd(&lcur[dv >> 8], 1);
    stage[slot] = (uint32_t)sv | ((uint32_t)dv << 16);
  }
  __syncthreads();
  for (int i = t; i < myE; i += 256) {
    const uint32_t sd = stage[i];
    const int b = sd >> 24;  // dst>>8
    staged[cbase[b] + (i - lstart[b])] = sd;
  }
}

__global__ __launch_bounds__(256) void bucket_csr_kernel(const uint32_t* __restrict__ staged,
                                                         const int* __restrict__ bucket_offs,
                                                         int* __restrict__ offs,
                                                         float* __restrict__ dinv, int n) {
  __shared__ int cnt[256], s[256];
  const int t = threadIdx.x, b = blockIdx.x;
  cnt[t] = 0;
  __syncthreads();
  const int ebeg = bucket_offs[b], eend = bucket_offs[b + 1];
  for (int i = ebeg + t; i < eend; i += 256) atomicAdd(&cnt[(staged[i] >> 16) & 255], 1);
  __syncthreads();
  const int c = cnt[t];
  s[t] = c;
  __syncthreads();
  for (int off = 1; off < 256; off <<= 1) {
    int v = (t >= off) ? s[t - off] : 0;
    __syncthreads();
    s[t] += v;
    __syncthreads();
  }
  const int node = (b << 8) + t;
  if (node < n) {
    offs[node] = ebeg + s[t] - c;
    dinv[node] = rsqrtf((float)(c + 1));  // +1 self-loop
  }
}

// epair word = src | (bf16(norm) << 16)
__global__ __launch_bounds__(256) void bucket_fill_kernel(const uint32_t* __restrict__ staged,
                                                          const int* __restrict__ bucket_offs,
                                                          const float* __restrict__ dinv,
                                                          uint32_t* __restrict__ epk, int n) {
  __shared__ int cnt[256], s[256], cur[256];
  const int t = threadIdx.x, b = blockIdx.x;
  cnt[t] = 0;
  __syncthreads();
  const int ebeg = bucket_offs[b], eend = bucket_offs[b + 1];
  for (int i = ebeg + t; i < eend; i += 256) atomicAdd(&cnt[(staged[i] >> 16) & 255], 1);
  __syncthreads();
  const int c = cnt[t];
  s[t] = c;
  __syncthreads();
  for (int off = 1; off < 256; off <<= 1) {
    int v = (t >= off) ? s[t - off] : 0;
    __syncthreads();
    s[t] += v;
    __syncthreads();
  }
  cur[t] = ebeg + s[t] - c;
  __syncthreads();
  for (int i = ebeg + t; i < eend; i += 256) {
    const uint32_t sd = staged[i];
    const int sv = sd & 0xFFFF;
    const int dv = sd >> 16;
    const int pos = atomicAdd(&cur[dv & 255], 1);
    epk[pos] = (uint32_t)sv | ((uint32_t)f2bf(dinv[sv] * dinv[dv]) << 16);
  }
}

// ---------------- W pre-pack into MFMA B-fragment order ----------------
__global__ __launch_bounds__(256) void pack_w_kernel(const float* __restrict__ W,
                                                     ushort* __restrict__ Wp,
                                                     int K, int N, int NF) {
  const int idx  = blockIdx.x * blockDim.x + threadIdx.x;
  const int lane = idx & 63;
  const int nf   = (idx >> 6) % NF;
  const int g    = idx / (64 * NF);
  if (g * 32 >= K) return;
  const int n  = nf * 16 + (lane & 15);
  const int kb = g * 32 + (lane >> 4) * 8;
  ushort v[8];
#pragma unroll
  for (int j = 0; j < 8; ++j) {
    const float f = (n < N) ? W[(size_t)(kb + j) * N + n] : 0.f;
    v[j] = f2bf(f);
  }
  *(short8*)&Wp[((size_t)(g * NF + nf) * 64 + lane) * 8] = *(short8*)v;
}

// ---------------- MFMA GEMM (G1 only): C = A(f32) @ W, bf16 out ----------------
template <int NF>
__global__ __launch_bounds__(256) void mfma_gemm_kernel(const float* __restrict__ A,
                                                        const ushort* __restrict__ Wp,
                                                        ushort* __restrict__ C,
                                                        int M, int N, int K) {
  __shared__ ushort Atile[64 * 64];
  const int tid  = threadIdx.x;
  const int lane = tid & 63;
  const int wave = tid >> 6;
  const int brow = blockIdx.x * 64;

  f32x4 acc[NF];
#pragma unroll
  for (int nf = 0; nf < NF; ++nf) acc[nf] = (f32x4){0.f, 0.f, 0.f, 0.f};

  const int arow = wave * 16 + (lane & 15);
  const int ahi  = lane >> 4;
  const int row0 = tid >> 3;
  const int kc0  = tid & 7;

  for (int k0 = 0; k0 < K; k0 += 64) {
    if (k0) __syncthreads();
#pragma unroll
    for (int c = 0; c < 2; ++c) {
      const int row = row0 + c * 32;
      const int gr  = brow + row;
      short8 v = (short8){0, 0, 0, 0, 0, 0, 0, 0};
      if (gr < M) {
        const float* Ap = A + (size_t)gr * K + k0 + kc0 * 8;
        const float4 f0 = *(const float4*)Ap;
        const float4 f1 = *(const float4*)(Ap + 4);
        v[0] = (short)f2bf(f0.x); v[1] = (short)f2bf(f0.y);
        v[2] = (short)f2bf(f0.z); v[3] = (short)f2bf(f0.w);
        v[4] = (short)f2bf(f1.x); v[5] = (short)f2bf(f1.y);
        v[6] = (short)f2bf(f1.z); v[7] = (short)f2bf(f1.w);
      }
      *(short8*)&Atile[row * 64 + ((kc0 ^ (row & 7)) * 8)] = v;
    }
    __syncthreads();

    const int gbase = (k0 >> 5) * NF;
#pragma unroll
    for (int kk = 0; kk < 2; ++kk) {
      const int kc = kk * 4 + ahi;
      const short8 a =
          *(const short8*)&Atile[arow * 64 + ((kc ^ (arow & 7)) * 8)];
      const ushort* wp = Wp + ((size_t)(gbase + kk * NF) * 64 + lane) * 8;
#pragma unroll
      for (int nf = 0; nf < NF; ++nf) {
        const short8 b = *(const short8*)(wp + (size_t)nf * 64 * 8);
        acc[nf] = __builtin_amdgcn_mfma_f32_16x16x32_bf16(a, b, acc[nf], 0, 0, 0);
      }
    }
  }

  const int crow0 = brow + wave * 16 + (lane >> 4) * 4;
  const int ccol  = lane & 15;
#pragma unroll
  for (int nf = 0; nf < NF; ++nf) {
    const int col = nf * 16 + ccol;
    if (col < N) {
#pragma unroll
      for (int r = 0; r < 4; ++r) {
        const int row = crow0 + r;
        if (row < M) C[(size_t)row * N + col] = f2bf(acc[nf][r]);
      }
    }
  }
}

// ---------------- Fused agg -> GEMM, 16 waves/block, ONE node per wave ----------
// Gather geometry identical to agg4 (4 edge-groups x 16 lanes x 8 feats, 2x
// unrolled, 50000 waves total). After barrier, waves 0..NF-1 each compute one
// 16-col fragment of the 16x128 @ W GEMM (4 MFMAs). LSM epilogue optional.
template <int NF, bool BIAS_RELU_AGG, bool LSM>
__global__ __launch_bounds__(1024) void fused_agg_gemm_kernel(
    const ushort* __restrict__ h, const int* __restrict__ offsets,
    const uint32_t* __restrict__ epk, const float* __restrict__ dinv,
    const float* __restrict__ bias_agg, const ushort* __restrict__ Wp,
    const float* __restrict__ bias_out, void* __restrict__ Cv, int M, int N) {
  __shared__ ushort Atile[2][16 * 64];  // 4 KB: 16 rows x K=128 as two 64-k tiles
  __shared__ float  Lg[16][40];         // LSM logits staging
  const int tid  = threadIdx.x;
  const int lane = tid & 63;
  const int wave = tid >> 6;  // 0..15, one node per wave
  const int brow = blockIdx.x * 16;
  const int node = brow + wave;

  const int eg    = lane >> 4;
  const int l15   = lane & 15;
  const int f0    = l15 * 8;
  const int ktile = l15 >> 3;
  const int kca   = l15 & 7;

  // ---- phase 1: aggregate one node per wave ----
  float a8[8];
#pragma unroll
  for (int j = 0; j < 8; ++j) a8[j] = 0.f;
  if (node < M) {
    const int start = offsets[node];
    const int end   = offsets[node + 1];
    for (int eb = start; eb < end; eb += 8) {
      const int e0 = eb + eg;
      const int e1 = e0 + 4;
      if (e0 < end) {
        const uint32_t p0 = epk[e0];
        const float    w0 = bf2f((ushort)(p0 >> 16));
        const short8   hv0 = *(const short8*)&h[(size_t)(p0 & 0xFFFF) * 128 + f0];
        if (e1 < end) {
          const uint32_t p1 = epk[e1];
          const float    w1 = bf2f((ushort)(p1 >> 16));
          const short8   hv1 = *(const short8*)&h[(size_t)(p1 & 0xFFFF) * 128 + f0];
#pragma unroll
          for (int j = 0; j < 8; ++j) {
            a8[j] = fmaf(bf2f((ushort)hv0[j]), w0, a8[j]);
            a8[j] = fmaf(bf2f((ushort)hv1[j]), w1, a8[j]);
          }
        } else {
#pragma unroll
          for (int j = 0; j < 8; ++j) a8[j] = fmaf(bf2f((ushort)hv0[j]), w0, a8[j]);
        }
      }
    }
#pragma unroll
    for (int j = 0; j < 8; ++j) {
      a8[j] += __shfl_xor(a8[j], 16, 64);
      a8[j] += __shfl_xor(a8[j], 32, 64);
    }
  }
  if (eg == 0) {
    ushort o[8];
    if (node < M) {
      const float di  = dinv[node];
      const float di2 = di * di;
      const short8 hs = *(const short8*)&h[(size_t)node * 128 + f0];
#pragma unroll
      for (int j = 0; j < 8; ++j) {
        float a = fmaf(bf2f((ushort)hs[j]), di2, a8[j]);
        if (BIAS_RELU_AGG) a = fmaxf(a + bias_agg[f0 + j], 0.f);
        o[j] = f2bf(a);
      }
    } else {
#pragma unroll
      for (int j = 0; j < 8; ++j) o[j] = 0;
    }
    *(short8*)&Atile[ktile][wave * 64 + ((kca ^ (wave & 7)) << 3)] = *(short8*)o;
  }
  __syncthreads();

  // ---- phase 2: waves 0..NF-1 each do one col-fragment (4 MFMAs) ----
  if (wave < NF) {
    const int nf = wave;
    f32x4 acc = (f32x4){0.f, 0.f, 0.f, 0.f};
    const int arow = lane & 15;
    const int ahi  = lane >> 4;
#pragma unroll
    for (int kt = 0; kt < 2; ++kt) {
#pragma unroll
      for (int kk = 0; kk < 2; ++kk) {
        const int kc = kk * 4 + ahi;
        const short8 a =
            *(const short8*)&Atile[kt][arow * 64 + ((kc ^ (arow & 7)) * 8)];
        const int g = kt * 2 + kk;
        const short8 b = *(const short8*)(Wp + ((size_t)(g * NF + nf) * 64 + lane) * 8);
        acc = __builtin_amdgcn_mfma_f32_16x16x32_bf16(a, b, acc, 0, 0, 0);
      }
    }
    const int ccol = lane & 15;
    const int r0   = (lane >> 4) * 4;
    const int col  = nf * 16 + ccol;
    if constexpr (!LSM) {
      ushort* C = (ushort*)Cv;
      if (col < N) {
#pragma unroll
        for (int r = 0; r < 4; ++r) {
          const int row = brow + r0 + r;
          if (row < M) C[(size_t)row * N + col] = f2bf(acc[r]);
        }
      }
    } else {
      if (col < N) {
        const float bv = bias_out[col];
#pragma unroll
        for (int r = 0; r < 4; ++r) Lg[r0 + r][col] = acc[r] + bv;
      }
    }
  }
  if constexpr (LSM) {
    __syncthreads();
    if (wave == 0) {
      float* out = (float*)Cv;
      const bool act = lane < N;  // N = 40
      for (int r = 0; r < 16; ++r) {
        const int row = brow + r;
        float v = act ? Lg[r][lane] : -INFINITY;
        float m = v;
#pragma unroll
        for (int o = 32; o >= 1; o >>= 1) m = fmaxf(m, __shfl_xor(m, o, 64));
        float ex = act ? expf(v - m) : 0.f;
        float s = ex;
#pragma unroll
        for (int o = 32; o >= 1; o >>= 1) s += __shfl_xor(s, o, 64);
        if (act && row < M) out[(size_t)row * N + lane] = v - m - logf(s);
      }
    }
  }
}

// ---------------- Standalone aggregation (layer 2) ----------------
template <bool BIAS_RELU>
__global__ __launch_bounds__(256) void agg4_kernel(const ushort* __restrict__ h,
                                                   const int* __restrict__ offsets,
                                                   const uint32_t* __restrict__ epk,
                                                   const float* __restrict__ dinv,
                                                   const float* __restrict__ bias,
                                                   ushort* __restrict__ out, int n) {
  const int wave = threadIdx.x >> 6;
  const int lane = threadIdx.x & 63;
  const int node = blockIdx.x * 4 + wave;
  if (node >= n) return;
  const int eg = lane >> 4;
  const int f0 = (lane & 15) * 8;

  float acc[8];
#pragma unroll
  for (int j = 0; j < 8; ++j) acc[j] = 0.f;

  const int start = offsets[node];
  const int end   = offsets[node + 1];
  for (int eb = start; eb < end; eb += 8) {
    const int e0 = eb + eg;
    const int e1 = e0 + 4;
    if (e0 < end) {
      const uint32_t p0 = epk[e0];
      const float    w0 = bf2f((ushort)(p0 >> 16));
      const short8   hv0 = *(const short8*)&h[(size_t)(p0 & 0xFFFF) * 128 + f0];
      if (e1 < end) {
        const uint32_t p1 = epk[e1];
        const float    w1 = bf2f((ushort)(p1 >> 16));
        const short8   hv1 = *(const short8*)&h[(size_t)(p1 & 0xFFFF) * 128 + f0];
#pragma unroll
        for (int j = 0; j < 8; ++j) {
          acc[j] = fmaf(bf2f((ushort)hv0[j]), w0, acc[j]);
          acc[j] = fmaf(bf2f((ushort)hv1[j]), w1, acc[j]);
        }
      } else {
#pragma unroll
        for (int j = 0; j < 8; ++j) acc[j] = fmaf(bf2f((ushort)hv0[j]), w0, acc[j]);
      }
    }
  }
#pragma unroll
  for (int j = 0; j < 8; ++j) {
    acc[j] += __shfl_xor(acc[j], 16, 64);
    acc[j] += __shfl_xor(acc[j], 32, 64);
  }
  if (eg == 0) {
    const float di  = dinv[node];
    const float di2 = di * di;
    const short8 hs = *(const short8*)&h[(size_t)node * 128 + f0];
    ushort o[8];
#pragma unroll
    for (int j = 0; j < 8; ++j) {
      float a = fmaf(bf2f((ushort)hs[j]), di2, acc[j]);
      if (BIAS_RELU) a = fmaxf(a + bias[f0 + j], 0.f);
      o[j] = f2bf(a);
    }
    *(short8*)&out[(size_t)node * 128 + f0] = *(short8*)o;
  }
}

extern "C" void kernel_launch(void* const* d_in, const int* in_sizes, int n_in,
                              void* d_out, int out_size, void* d_ws, size_t ws_size,
                              hipStream_t stream) {
  const float* x  = (const float*)d_in[0];
  const int*   ei = (const int*)d_in[1];
  const float* W1 = (const float*)d_in[2];
  const float* b1 = (const float*)d_in[3];
  const float* W2 = (const float*)d_in[4];
  const float* b2 = (const float*)d_in[5];
  const float* W3 = (const float*)d_in[6];
  const float* b3 = (const float*)d_in[7];

  const int h1   = in_sizes[3];        // 128
  const int h2   = in_sizes[5];        // 128
  const int ncls = in_sizes[7];        // 40
  const int fin  = in_sizes[2] / h1;   // 256
  const int n    = in_sizes[0] / fin;  // 50000 (packing requires n <= 65536)
  const int E    = in_sizes[1] / 2;    // 800000

  const int* src = ei;
  const int* dst = ei + E;

  char* p = (char*)d_ws;
  auto alloc = [&](size_t bytes) {
    char* r = p;
    p += (bytes + 255) & ~size_t(255);
    return r;
  };
  float*    dinv   = (float*)alloc((size_t)n * 4);
  int*      offs   = (int*)alloc((size_t)(n + 1) * 4);
  int*      bcount = (int*)alloc(256 * 4);
  int*      boffs  = (int*)alloc(257 * 4);
  int*      bcur   = (int*)alloc(256 * 4);
  uint32_t* staged = (uint32_t*)alloc((size_t)E * 4);
  uint32_t* epk    = (uint32_t*)alloc((size_t)E * 4);
  ushort*   hf     = (ushort*)alloc((size_t)n * h1 * 2);  // G1 out / a2 out
  ushort*   hg     = (ushort*)alloc((size_t)n * h1 * 2);  // F1' out
  ushort*   Wp1    = (ushort*)alloc((size_t)(fin / 32) * 8 * 64 * 8 * 2);
  ushort*   Wp2    = (ushort*)alloc((size_t)(h1 / 32) * 8 * 64 * 8 * 2);
  ushort*   Wp3    = (ushort*)alloc((size_t)(h2 / 32) * 3 * 64 * 8 * 2);

  const int nbuck = (n + 255) >> 8;        // 196
  const int ebw   = (E + EPB - 1) / EPB;   // 196

  // --- CSR build: 2-level bucket sort ---
  hipMemsetAsync(bcount, 0, 256 * 4, stream);
  bucket_hist_kernel<<<ebw, 256, 0, stream>>>(dst, bcount, E);
  bucket_scan_kernel<<<1, 256, 0, stream>>>(bcount, boffs, bcur, offs, nbuck, n);
  bucket_scatter_kernel<<<ebw, 256, 0, stream>>>(src, dst, bcur, staged, E, nbuck);
  bucket_csr_kernel<<<nbuck, 256, 0, stream>>>(staged, boffs, offs, dinv, n);
  bucket_fill_kernel<<<nbuck, 256, 0, stream>>>(staged, boffs, dinv, epk, n);

  // --- pack weights (fragment order, bf16) ---
  {
    int t1 = (fin / 32) * 8 * 64;
    int t2 = (h1 / 32) * 8 * 64;
    int t3 = (h2 / 32) * 3 * 64;
    pack_w_kernel<<<(t1 + 255) / 256, 256, 0, stream>>>(W1, Wp1, fin, h1, 8);
    pack_w_kernel<<<(t2 + 255) / 256, 256, 0, stream>>>(W2, Wp2, h1, h2, 8);
    pack_w_kernel<<<(t3 + 255) / 256, 256, 0, stream>>>(W3, Wp3, h2, ncls, 3);
  }

  const int gblocks = (n + 63) / 64;
  const int ablocks = (n + 3) / 4;
  const int fblocks = (n + 15) / 16;

  // --- G1: x @ W1 -> hf ---
  mfma_gemm_kernel<8><<<gblocks, 256, 0, stream>>>(x, Wp1, hf, n, h1, fin);
  // --- F1': [agg(hf,+b1,relu) @ W2] -> hg (fused, 1 node/wave) ---
  fused_agg_gemm_kernel<8, true, false><<<fblocks, 1024, 0, stream>>>(
      hf, offs, epk, dinv, b1, Wp2, nullptr, hg, n, h2);
  // --- a2: agg(hg,+b2,relu) -> hf ---
  agg4_kernel<true><<<ablocks, 256, 0, stream>>>(hg, offs, epk, dinv, b2, hf, n);
  // --- F2': [agg(hf) @ W3 +b3 +log_softmax] -> out (fused) ---
  fused_agg_gemm_kernel<3, false, true><<<fblocks, 1024, 0, stream>>>(
      hf, offs, epk, dinv, nullptr, Wp3, b3, d_out, n, ncls);
}

// Round 11
// 207.699 us; speedup vs baseline: 1.2617x; 1.1444x over previous
//
#include <hip/hip_runtime.h>
#include <cstdint>
#include <cstddef>
#include <cmath>

// ---------------------------------------------------------------------------
// GCN: 3 layers. CSR (by dst) built once, then:
//   G1: x @ W1 -> bufA          (bf16 MFMA)
//   a1: agg(bufA,+b1,relu) -> bufB
//   G2: bufB @ W2 -> bufA
//   a2: agg(bufA,+b2,relu) -> bufB
//   G3: bufB @ W3 -> hs [n,64] bf16 (cols 40..63 zero)   <- layer-3 commuted
//   a3: agg40(hs) + b3 + log_softmax -> out              <- 128B rows, 2x fewer
//                                                           gather bytes than 128-wide agg
// R7: bucket-sort CSR. R8: aggs at below-L2 byte floor. R9/R10 FAILED: fusing
//   agg+GEMM loses to barrier skew (block waits for slowest node) -- reverted.
// R11: layer-3 GEMM-first (gather 40->64-padded bf16 logits, not 128-wide h).
// ---------------------------------------------------------------------------

typedef __attribute__((ext_vector_type(8))) short short8;
typedef __attribute__((ext_vector_type(4))) short short4v;
typedef __attribute__((ext_vector_type(4))) float f32x4;

constexpr int EPB = 4096;  // edges per workgroup in bucket hist/scatter

__device__ __forceinline__ ushort f2bf(float f) {
  union { float f; uint32_t u; } x; x.f = f;
  uint32_t r = x.u + 0x7fffu + ((x.u >> 16) & 1u);  // RNE
  return (ushort)(r >> 16);
}
__device__ __forceinline__ float bf2f(ushort u) {
  union { uint32_t u; float f; } x; x.u = ((uint32_t)u) << 16;
  return x.f;
}

// ---------------- CSR build: 2-level bucket sort (packed u32 words) ----------------
__global__ __launch_bounds__(256) void bucket_hist_kernel(const int* __restrict__ dst,
                                                          int* __restrict__ bucket_count,
                                                          int E) {
  __shared__ int h[256];
  const int t  = threadIdx.x;
  const int e0 = blockIdx.x * EPB;
  const int myE = min(EPB, E - e0);
  h[t] = 0;
  __syncthreads();
  for (int i = t; i < myE; i += 256) atomicAdd(&h[dst[e0 + i] >> 8], 1);
  __syncthreads();
  if (h[t]) atomicAdd(&bucket_count[t], h[t]);
}

__global__ __launch_bounds__(256) void bucket_scan_kernel(const int* __restrict__ bucket_count,
                                                          int* __restrict__ bucket_offs,
                                                          int* __restrict__ bucket_cursor,
                                                          int* __restrict__ offs,
                                                          int nbuck, int n) {
  __shared__ int s[256];
  const int t = threadIdx.x;
  const int c = (t < nbuck) ? bucket_count[t] : 0;
  s[t] = c;
  __syncthreads();
  for (int off = 1; off < 256; off <<= 1) {
    int v = (t >= off) ? s[t - off] : 0;
    __syncthreads();
    s[t] += v;
    __syncthreads();
  }
  if (t < nbuck) {
    bucket_offs[t]   = s[t] - c;
    bucket_cursor[t] = s[t] - c;
  }
  if (t == 255) {
    bucket_offs[nbuck] = s[255];
    offs[n] = s[255];
  }
}

// staged word = src | (dst << 16)   (src,dst < 65536)
__global__ __launch_bounds__(256) void bucket_scatter_kernel(const int* __restrict__ src,
                                                             const int* __restrict__ dst,
                                                             int* __restrict__ bucket_cursor,
                                                             uint32_t* __restrict__ staged,
                                                             int E, int nbuck) {
  __shared__ int hist[256], s[256], lstart[256], cbase[256], lcur[256];
  __shared__ uint32_t stage[EPB];  // 16 KB
  const int t  = threadIdx.x;
  const int e0 = blockIdx.x * EPB;
  const int myE = min(EPB, E - e0);
  hist[t] = 0;
  __syncthreads();
  for (int i = t; i < myE; i += 256) atomicAdd(&hist[dst[e0 + i] >> 8], 1);
  __syncthreads();
  const int c = hist[t];
  s[t] = c;
  __syncthreads();
  for (int off = 1; off < 256; off <<= 1) {
    int v = (t >= off) ? s[t - off] : 0;
    __syncthreads();
    s[t] += v;
    __syncthreads();
  }
  lstart[t] = s[t] - c;
  lcur[t]   = s[t] - c;
  cbase[t]  = (c > 0 && t < nbuck) ? atomicAdd(&bucket_cursor[t], c) : 0;
  __syncthreads();
  for (int i = t; i < myE; i += 256) {
    const int sv = src[e0 + i], dv = dst[e0 + i];
    const int slot = atomicAdd(&lcur[dv >> 8], 1);
    stage[slot] = (uint32_t)sv | ((uint32_t)dv << 16);
  }
  __syncthreads();
  for (int i = t; i < myE; i += 256) {
    const uint32_t sd = stage[i];
    const int b = sd >> 24;  // dst>>8
    staged[cbase[b] + (i - lstart[b])] = sd;
  }
}

__global__ __launch_bounds__(256) void bucket_csr_kernel(const uint32_t* __restrict__ staged,
                                                         const int* __restrict__ bucket_offs,
                                                         int* __restrict__ offs,
                                                         float* __restrict__ dinv, int n) {
  __shared__ int cnt[256], s[256];
  const int t = threadIdx.x, b = blockIdx.x;
  cnt[t] = 0;
  __syncthreads();
  const int ebeg = bucket_offs[b], eend = bucket_offs[b + 1];
  for (int i = ebeg + t; i < eend; i += 256) atomicAdd(&cnt[(staged[i] >> 16) & 255], 1);
  __syncthreads();
  const int c = cnt[t];
  s[t] = c;
  __syncthreads();
  for (int off = 1; off < 256; off <<= 1) {
    int v = (t >= off) ? s[t - off] : 0;
    __syncthreads();
    s[t] += v;
    __syncthreads();
  }
  const int node = (b << 8) + t;
  if (node < n) {
    offs[node] = ebeg + s[t] - c;
    dinv[node] = rsqrtf((float)(c + 1));  // +1 self-loop
  }
}

// epair word = src | (bf16(norm) << 16)
__global__ __launch_bounds__(256) void bucket_fill_kernel(const uint32_t* __restrict__ staged,
                                                          const int* __restrict__ bucket_offs,
                                                          const float* __restrict__ dinv,
                                                          uint32_t* __restrict__ epk, int n) {
  __shared__ int cnt[256], s[256], cur[256];
  const int t = threadIdx.x, b = blockIdx.x;
  cnt[t] = 0;
  __syncthreads();
  const int ebeg = bucket_offs[b], eend = bucket_offs[b + 1];
  for (int i = ebeg + t; i < eend; i += 256) atomicAdd(&cnt[(staged[i] >> 16) & 255], 1);
  __syncthreads();
  const int c = cnt[t];
  s[t] = c;
  __syncthreads();
  for (int off = 1; off < 256; off <<= 1) {
    int v = (t >= off) ? s[t - off] : 0;
    __syncthreads();
    s[t] += v;
    __syncthreads();
  }
  cur[t] = ebeg + s[t] - c;
  __syncthreads();
  for (int i = ebeg + t; i < eend; i += 256) {
    const uint32_t sd = staged[i];
    const int sv = sd & 0xFFFF;
    const int dv = sd >> 16;
    const int pos = atomicAdd(&cur[dv & 255], 1);
    epk[pos] = (uint32_t)sv | ((uint32_t)f2bf(dinv[sv] * dinv[dv]) << 16);
  }
}

// ---------------- W pre-pack into MFMA B-fragment order ----------------
__global__ __launch_bounds__(256) void pack_w_kernel(const float* __restrict__ W,
                                                     ushort* __restrict__ Wp,
                                                     int K, int N, int NF) {
  const int idx  = blockIdx.x * blockDim.x + threadIdx.x;
  const int lane = idx & 63;
  const int nf   = (idx >> 6) % NF;
  const int g    = idx / (64 * NF);
  if (g * 32 >= K) return;
  const int n  = nf * 16 + (lane & 15);
  const int kb = g * 32 + (lane >> 4) * 8;
  ushort v[8];
#pragma unroll
  for (int j = 0; j < 8; ++j) {
    const float f = (n < N) ? W[(size_t)(kb + j) * N + n] : 0.f;
    v[j] = f2bf(f);
  }
  *(short8*)&Wp[((size_t)(g * NF + nf) * 64 + lane) * 8] = *(short8*)v;
}

// ---------------- MFMA GEMM: C[M,Npad] = A[M,K] @ W[K,Npad], bf16 out ----------------
template <int NF, bool AF32>
__global__ __launch_bounds__(256) void mfma_gemm_kernel(const void* __restrict__ Av,
                                                        const ushort* __restrict__ Wp,
                                                        ushort* __restrict__ C,
                                                        int M, int N, int K) {
  __shared__ ushort Atile[64 * 64];
  const int tid  = threadIdx.x;
  const int lane = tid & 63;
  const int wave = tid >> 6;
  const int brow = blockIdx.x * 64;

  f32x4 acc[NF];
#pragma unroll
  for (int nf = 0; nf < NF; ++nf) acc[nf] = (f32x4){0.f, 0.f, 0.f, 0.f};

  const int arow = wave * 16 + (lane & 15);
  const int ahi  = lane >> 4;
  const int row0 = tid >> 3;
  const int kc0  = tid & 7;

  for (int k0 = 0; k0 < K; k0 += 64) {
    if (k0) __syncthreads();
#pragma unroll
    for (int c = 0; c < 2; ++c) {
      const int row = row0 + c * 32;
      const int gr  = brow + row;
      short8 v = (short8){0, 0, 0, 0, 0, 0, 0, 0};
      if (gr < M) {
        if constexpr (AF32) {
          const float* A = (const float*)Av + (size_t)gr * K + k0 + kc0 * 8;
          const float4 f0 = *(const float4*)A;
          const float4 f1 = *(const float4*)(A + 4);
          v[0] = (short)f2bf(f0.x); v[1] = (short)f2bf(f0.y);
          v[2] = (short)f2bf(f0.z); v[3] = (short)f2bf(f0.w);
          v[4] = (short)f2bf(f1.x); v[5] = (short)f2bf(f1.y);
          v[6] = (short)f2bf(f1.z); v[7] = (short)f2bf(f1.w);
        } else {
          v = *(const short8*)((const ushort*)Av + (size_t)gr * K + k0 + kc0 * 8);
        }
      }
      *(short8*)&Atile[row * 64 + ((kc0 ^ (row & 7)) * 8)] = v;
    }
    __syncthreads();

    const int gbase = (k0 >> 5) * NF;
#pragma unroll
    for (int kk = 0; kk < 2; ++kk) {
      const int kc = kk * 4 + ahi;
      const short8 a =
          *(const short8*)&Atile[arow * 64 + ((kc ^ (arow & 7)) * 8)];
      const ushort* wp = Wp + ((size_t)(gbase + kk * NF) * 64 + lane) * 8;
#pragma unroll
      for (int nf = 0; nf < NF; ++nf) {
        const short8 b = *(const short8*)(wp + (size_t)nf * 64 * 8);
        acc[nf] = __builtin_amdgcn_mfma_f32_16x16x32_bf16(a, b, acc[nf], 0, 0, 0);
      }
    }
  }

  const int crow0 = brow + wave * 16 + (lane >> 4) * 4;
  const int ccol  = lane & 15;
#pragma unroll
  for (int nf = 0; nf < NF; ++nf) {
    const int col = nf * 16 + ccol;
#pragma unroll
    for (int r = 0; r < 4; ++r) {
      const int row = crow0 + r;
      if (row < M) C[(size_t)row * N + col] = f2bf(acc[nf][r]);
    }
  }
}

// ---------------- Aggregation (128-wide): 4 edge-groups x 16 lanes x 8 feats ----------
template <bool BIAS_RELU>
__global__ __launch_bounds__(256) void agg4_kernel(const ushort* __restrict__ h,
                                                   const int* __restrict__ offsets,
                                                   const uint32_t* __restrict__ epk,
                                                   const float* __restrict__ dinv,
                                                   const float* __restrict__ bias,
                                                   ushort* __restrict__ out, int n) {
  const int wave = threadIdx.x >> 6;
  const int lane = threadIdx.x & 63;
  const int node = blockIdx.x * 4 + wave;
  if (node >= n) return;
  const int eg = lane >> 4;
  const int f0 = (lane & 15) * 8;

  float acc[8];
#pragma unroll
  for (int j = 0; j < 8; ++j) acc[j] = 0.f;

  const int start = offsets[node];
  const int end   = offsets[node + 1];
  for (int eb = start; eb < end; eb += 8) {
    const int e0 = eb + eg;
    const int e1 = e0 + 4;
    if (e0 < end) {
      const uint32_t p0 = epk[e0];
      const float    w0 = bf2f((ushort)(p0 >> 16));
      const short8   hv0 = *(const short8*)&h[(size_t)(p0 & 0xFFFF) * 128 + f0];
      if (e1 < end) {
        const uint32_t p1 = epk[e1];
        const float    w1 = bf2f((ushort)(p1 >> 16));
        const short8   hv1 = *(const short8*)&h[(size_t)(p1 & 0xFFFF) * 128 + f0];
#pragma unroll
        for (int j = 0; j < 8; ++j) {
          acc[j] = fmaf(bf2f((ushort)hv0[j]), w0, acc[j]);
          acc[j] = fmaf(bf2f((ushort)hv1[j]), w1, acc[j]);
        }
      } else {
#pragma unroll
        for (int j = 0; j < 8; ++j) acc[j] = fmaf(bf2f((ushort)hv0[j]), w0, acc[j]);
      }
    }
  }
#pragma unroll
  for (int j = 0; j < 8; ++j) {
    acc[j] += __shfl_xor(acc[j], 16, 64);
    acc[j] += __shfl_xor(acc[j], 32, 64);
  }
  if (eg == 0) {
    const float di  = dinv[node];
    const float di2 = di * di;
    const short8 hs = *(const short8*)&h[(size_t)node * 128 + f0];
    ushort o[8];
#pragma unroll
    for (int j = 0; j < 8; ++j) {
      float a = fmaf(bf2f((ushort)hs[j]), di2, acc[j]);
      if (BIAS_RELU) a = fmaxf(a + bias[f0 + j], 0.f);
      o[j] = f2bf(a);
    }
    *(short8*)&out[(size_t)node * 128 + f0] = *(short8*)o;
  }
}

// ---------------- Final agg over 64-padded bf16 logits + bias + log_softmax -------
// 4 nodes/block, 1 wave/node; 4 edge-groups x 16 lanes x 4 cols (ushort4 = 8B).
// Rows are 128B (64 bf16), so each gather touches exactly 2 cache lines.
__global__ __launch_bounds__(256) void agg40_lsm_kernel(const ushort* __restrict__ h,
                                                        const int* __restrict__ offsets,
                                                        const uint32_t* __restrict__ epk,
                                                        const float* __restrict__ dinv,
                                                        const float* __restrict__ bias,
                                                        float* __restrict__ out, int n) {
  const int wave = threadIdx.x >> 6;
  const int lane = threadIdx.x & 63;
  const int node = blockIdx.x * 4 + wave;
  if (node >= n) return;
  const int eg  = lane >> 4;
  const int l15 = lane & 15;
  const int f0  = l15 * 4;  // cols f0..f0+3 of 64 (only 0..39 meaningful)

  float acc[4] = {0.f, 0.f, 0.f, 0.f};
  const int start = offsets[node];
  const int end   = offsets[node + 1];
  for (int eb = start; eb < end; eb += 8) {
    const int e0 = eb + eg;
    const int e1 = e0 + 4;
    if (e0 < end) {
      const uint32_t p0 = epk[e0];
      const float    w0 = bf2f((ushort)(p0 >> 16));
      const short4v  hv0 = *(const short4v*)&h[(size_t)(p0 & 0xFFFF) * 64 + f0];
      if (e1 < end) {
        const uint32_t p1 = epk[e1];
        const float    w1 = bf2f((ushort)(p1 >> 16));
        const short4v  hv1 = *(const short4v*)&h[(size_t)(p1 & 0xFFFF) * 64 + f0];
#pragma unroll
        for (int j = 0; j < 4; ++j) {
          acc[j] = fmaf(bf2f((ushort)hv0[j]), w0, acc[j]);
          acc[j] = fmaf(bf2f((ushort)hv1[j]), w1, acc[j]);
        }
      } else {
#pragma unroll
        for (int j = 0; j < 4; ++j) acc[j] = fmaf(bf2f((ushort)hv0[j]), w0, acc[j]);
      }
    }
  }
#pragma unroll
  for (int j = 0; j < 4; ++j) {
    acc[j] += __shfl_xor(acc[j], 16, 64);
    acc[j] += __shfl_xor(acc[j], 32, 64);
  }
  if (eg == 0) {
    const bool valid = l15 < 10;  // cols 0..39 (40 = 10 lanes x 4)
    const float di  = dinv[node];
    const float di2 = di * di;
    const short4v hs = *(const short4v*)&h[(size_t)node * 64 + f0];
    float v[4];
    if (valid) {
#pragma unroll
      for (int j = 0; j < 4; ++j)
        v[j] = fmaf(bf2f((ushort)hs[j]), di2, acc[j]) + bias[f0 + j];
    } else {
#pragma unroll
      for (int j = 0; j < 4; ++j) v[j] = -INFINITY;
    }
    // log_softmax over the 40 cols (16-lane group reduce)
    float m = fmaxf(fmaxf(v[0], v[1]), fmaxf(v[2], v[3]));
#pragma unroll
    for (int o = 8; o >= 1; o >>= 1) m = fmaxf(m, __shfl_xor(m, o, 64));
    float s = valid ? (expf(v[0] - m) + expf(v[1] - m) + expf(v[2] - m) + expf(v[3] - m)) : 0.f;
#pragma unroll
    for (int o = 8; o >= 1; o >>= 1) s += __shfl_xor(s, o, 64);
    const float mls = m + logf(s);
    if (valid) {
      float4 o4 = make_float4(v[0] - mls, v[1] - mls, v[2] - mls, v[3] - mls);
      *(float4*)&out[(size_t)node * 40 + f0] = o4;
    }
  }
}

extern "C" void kernel_launch(void* const* d_in, const int* in_sizes, int n_in,
                              void* d_out, int out_size, void* d_ws, size_t ws_size,
                              hipStream_t stream) {
  const float* x  = (const float*)d_in[0];
  const int*   ei = (const int*)d_in[1];
  const float* W1 = (const float*)d_in[2];
  const float* b1 = (const float*)d_in[3];
  const float* W2 = (const float*)d_in[4];
  const float* b2 = (const float*)d_in[5];
  const float* W3 = (const float*)d_in[6];
  const float* b3 = (const float*)d_in[7];

  const int h1   = in_sizes[3];        // 128
  const int h2   = in_sizes[5];        // 128
  const int ncls = in_sizes[7];        // 40
  const int fin  = in_sizes[2] / h1;   // 256
  const int n    = in_sizes[0] / fin;  // 50000 (packing requires n <= 65536)
  const int E    = in_sizes[1] / 2;    // 800000

  const int* src = ei;
  const int* dst = ei + E;

  char* p = (char*)d_ws;
  auto alloc = [&](size_t bytes) {
    char* r = p;
    p += (bytes + 255) & ~size_t(255);
    return r;
  };
  float*    dinv   = (float*)alloc((size_t)n * 4);
  int*      offs   = (int*)alloc((size_t)(n + 1) * 4);
  int*      bcount = (int*)alloc(256 * 4);
  int*      boffs  = (int*)alloc(257 * 4);
  int*      bcur   = (int*)alloc(256 * 4);
  uint32_t* staged = (uint32_t*)alloc((size_t)E * 4);
  uint32_t* epk    = (uint32_t*)alloc((size_t)E * 4);
  ushort*   bufA   = (ushort*)alloc((size_t)n * h1 * 2);  // G1/G2 out
  ushort*   bufB   = (ushort*)alloc((size_t)n * h1 * 2);  // a1/a2 out
  ushort*   hs     = (ushort*)alloc((size_t)n * 64 * 2);  // G3 out (padded logits)
  ushort*   Wp1    = (ushort*)alloc((size_t)(fin / 32) * 8 * 64 * 8 * 2);
  ushort*   Wp2    = (ushort*)alloc((size_t)(h1 / 32) * 8 * 64 * 8 * 2);
  ushort*   Wp3    = (ushort*)alloc((size_t)(h2 / 32) * 4 * 64 * 8 * 2);

  const int nbuck = (n + 255) >> 8;        // 196
  const int ebw   = (E + EPB - 1) / EPB;   // 196

  // --- CSR build: 2-level bucket sort ---
  hipMemsetAsync(bcount, 0, 256 * 4, stream);
  bucket_hist_kernel<<<ebw, 256, 0, stream>>>(dst, bcount, E);
  bucket_scan_kernel<<<1, 256, 0, stream>>>(bcount, boffs, bcur, offs, nbuck, n);
  bucket_scatter_kernel<<<ebw, 256, 0, stream>>>(src, dst, bcur, staged, E, nbuck);
  bucket_csr_kernel<<<nbuck, 256, 0, stream>>>(staged, boffs, offs, dinv, n);
  bucket_fill_kernel<<<nbuck, 256, 0, stream>>>(staged, boffs, dinv, epk, n);

  // --- pack weights (fragment order, bf16) ---
  {
    int t1 = (fin / 32) * 8 * 64;  // W1: K=256, NF=8
    int t2 = (h1 / 32) * 8 * 64;   // W2: K=128, NF=8
    int t3 = (h2 / 32) * 4 * 64;   // W3: K=128, NF=4 (N=40 padded to 64)
    pack_w_kernel<<<(t1 + 255) / 256, 256, 0, stream>>>(W1, Wp1, fin, h1, 8);
    pack_w_kernel<<<(t2 + 255) / 256, 256, 0, stream>>>(W2, Wp2, h1, h2, 8);
    pack_w_kernel<<<(t3 + 255) / 256, 256, 0, stream>>>(W3, Wp3, h2, ncls, 4);
  }

  const int gblocks = (n + 63) / 64;
  const int ablocks = (n + 3) / 4;

  // --- layer 1 ---
  mfma_gemm_kernel<8, true><<<gblocks, 256, 0, stream>>>(x, Wp1, bufA, n, h1, fin);
  agg4_kernel<true><<<ablocks, 256, 0, stream>>>(bufA, offs, epk, dinv, b1, bufB, n);
  // --- layer 2 ---
  mfma_gemm_kernel<8, false><<<gblocks, 256, 0, stream>>>(bufB, Wp2, bufA, n, h2, h1);
  agg4_kernel<true><<<ablocks, 256, 0, stream>>>(bufA, offs, epk, dinv, b2, bufB, n);
  // --- layer 3: GEMM first (40 cols padded to 64), then agg + bias + lsm ---
  mfma_gemm_kernel<4, false><<<gblocks, 256, 0, stream>>>(bufB, Wp3, hs, n, 64, h2);
  agg40_lsm_kernel<<<ablocks, 256, 0, stream>>>(hs, offs, epk, dinv, b3,
                                                (float*)d_out, n);
}

// Round 12
// 199.285 us; speedup vs baseline: 1.3150x; 1.0422x over previous
//
#include <hip/hip_runtime.h>
#include <cstdint>
#include <cstddef>
#include <cmath>

// ---------------------------------------------------------------------------
// GCN: 3 layers. CSR (by dst) built once, then:
//   G1: x @ W1 -> bufA          (bf16 MFMA)
//   a1: agg(bufA,+b1,relu) -> bufB
//   G2: bufB @ W2 -> bufA
//   a2: agg(bufA,+b2,relu) -> bufB
//   G3: bufB @ W3 -> hs [n,64] bf16 (cols 40..63 zero)   (layer-3 commuted)
//   a3: agg40(hs) + b3 + log_softmax -> out
// R7: bucket-sort CSR. R8: aggs at below-L2 gather byte floor (~84MB, 2.5TB/s;
//   MLP null-test proved BW-bound). R9/R10 FAILED: agg+GEMM fusion loses to
//   barrier skew. R11: layer-3 GEMM-first (128B logits rows).
// R12: CSR de-duplication -- hist saves per-wg counts (scatter skips its hist
//   pass); fill's cursor = offs[node] (skips hist+scan entirely; scatter order
//   unchanged -> bitwise-identical epk); 3 pack_w launches merged into 1.
// ---------------------------------------------------------------------------

typedef __attribute__((ext_vector_type(8))) short short8;
typedef __attribute__((ext_vector_type(4))) short short4v;
typedef __attribute__((ext_vector_type(4))) float f32x4;

constexpr int EPB = 4096;  // edges per workgroup in bucket hist/scatter

__device__ __forceinline__ ushort f2bf(float f) {
  union { float f; uint32_t u; } x; x.f = f;
  uint32_t r = x.u + 0x7fffu + ((x.u >> 16) & 1u);  // RNE
  return (ushort)(r >> 16);
}
__device__ __forceinline__ float bf2f(ushort u) {
  union { uint32_t u; float f; } x; x.u = ((uint32_t)u) << 16;
  return x.f;
}

// ---------------- CSR build: 2-level bucket sort (packed u32 words) ----------------
// k1: per-wg LDS histogram; saves counts to global for k3 to reuse.
__global__ __launch_bounds__(256) void bucket_hist_kernel(const int* __restrict__ dst,
                                                          int* __restrict__ bucket_count,
                                                          int* __restrict__ wg_hist,
                                                          int E) {
  __shared__ int h[256];
  const int t  = threadIdx.x;
  const int e0 = blockIdx.x * EPB;
  const int myE = min(EPB, E - e0);
  h[t] = 0;
  __syncthreads();
  for (int i = t; i < myE; i += 256) atomicAdd(&h[dst[e0 + i] >> 8], 1);
  __syncthreads();
  wg_hist[blockIdx.x * 256 + t] = h[t];
  if (h[t]) atomicAdd(&bucket_count[t], h[t]);
}

__global__ __launch_bounds__(256) void bucket_scan_kernel(const int* __restrict__ bucket_count,
                                                          int* __restrict__ bucket_offs,
                                                          int* __restrict__ bucket_cursor,
                                                          int* __restrict__ offs,
                                                          int nbuck, int n) {
  __shared__ int s[256];
  const int t = threadIdx.x;
  const int c = (t < nbuck) ? bucket_count[t] : 0;
  s[t] = c;
  __syncthreads();
  for (int off = 1; off < 256; off <<= 1) {
    int v = (t >= off) ? s[t - off] : 0;
    __syncthreads();
    s[t] += v;
    __syncthreads();
  }
  if (t < nbuck) {
    bucket_offs[t]   = s[t] - c;
    bucket_cursor[t] = s[t] - c;
  }
  if (t == 255) {
    bucket_offs[nbuck] = s[255];
    offs[n] = s[255];
  }
}

// k3: LDS counting sort of EPB edges by bucket; counts preloaded from wg_hist.
// staged word = src | (dst << 16)   (src,dst < 65536)
__global__ __launch_bounds__(256) void bucket_scatter_kernel(const int* __restrict__ src,
                                                             const int* __restrict__ dst,
                                                             const int* __restrict__ wg_hist,
                                                             int* __restrict__ bucket_cursor,
                                                             uint32_t* __restrict__ staged,
                                                             int E, int nbuck) {
  __shared__ int s[256], lstart[256], cbase[256], lcur[256];
  __shared__ uint32_t stage[EPB];  // 16 KB
  const int t  = threadIdx.x;
  const int e0 = blockIdx.x * EPB;
  const int myE = min(EPB, E - e0);
  const int c = wg_hist[blockIdx.x * 256 + t];  // R12: no re-histogram
  s[t] = c;
  __syncthreads();
  for (int off = 1; off < 256; off <<= 1) {
    int v = (t >= off) ? s[t - off] : 0;
    __syncthreads();
    s[t] += v;
    __syncthreads();
  }
  lstart[t] = s[t] - c;
  lcur[t]   = s[t] - c;
  cbase[t]  = (c > 0 && t < nbuck) ? atomicAdd(&bucket_cursor[t], c) : 0;
  __syncthreads();
  for (int i = t; i < myE; i += 256) {
    const int sv = src[e0 + i], dv = dst[e0 + i];
    const int slot = atomicAdd(&lcur[dv >> 8], 1);
    stage[slot] = (uint32_t)sv | ((uint32_t)dv << 16);
  }
  __syncthreads();
  for (int i = t; i < myE; i += 256) {
    const uint32_t sd = stage[i];
    const int b = sd >> 24;  // dst>>8
    staged[cbase[b] + (i - lstart[b])] = sd;
  }
}

// k4: one wg per bucket: per-dst hist + scan -> offs, dinv (coalesced writes)
__global__ __launch_bounds__(256) void bucket_csr_kernel(const uint32_t* __restrict__ staged,
                                                         const int* __restrict__ bucket_offs,
                                                         int* __restrict__ offs,
                                                         float* __restrict__ dinv, int n) {
  __shared__ int cnt[256], s[256];
  const int t = threadIdx.x, b = blockIdx.x;
  cnt[t] = 0;
  __syncthreads();
  const int ebeg = bucket_offs[b], eend = bucket_offs[b + 1];
  for (int i = ebeg + t; i < eend; i += 256) atomicAdd(&cnt[(staged[i] >> 16) & 255], 1);
  __syncthreads();
  const int c = cnt[t];
  s[t] = c;
  __syncthreads();
  for (int off = 1; off < 256; off <<= 1) {
    int v = (t >= off) ? s[t - off] : 0;
    __syncthreads();
    s[t] += v;
    __syncthreads();
  }
  const int node = (b << 8) + t;
  if (node < n) {
    offs[node] = ebeg + s[t] - c;
    dinv[node] = rsqrtf((float)(c + 1));  // +1 self-loop
  }
}

// k5: exact-position scatter; cursor = offs[node] (R12: no hist/scan re-do).
// epair word = src | (bf16(norm) << 16). Scatter order identical to R11.
__global__ __launch_bounds__(256) void bucket_fill_kernel(const uint32_t* __restrict__ staged,
                                                          const int* __restrict__ bucket_offs,
                                                          const int* __restrict__ offs,
                                                          const float* __restrict__ dinv,
                                                          uint32_t* __restrict__ epk, int n) {
  __shared__ int cur[256];
  const int t = threadIdx.x, b = blockIdx.x;
  const int node = (b << 8) + t;
  cur[t] = (node < n) ? offs[node] : 0;
  __syncthreads();
  const int ebeg = bucket_offs[b], eend = bucket_offs[b + 1];
  for (int i = ebeg + t; i < eend; i += 256) {
    const uint32_t sd = staged[i];
    const int sv = sd & 0xFFFF;
    const int dv = sd >> 16;
    const int pos = atomicAdd(&cur[dv & 255], 1);
    epk[pos] = (uint32_t)sv | ((uint32_t)f2bf(dinv[sv] * dinv[dv]) << 16);
  }
}

// ---------------- All W pre-packs in one launch (MFMA B-fragment order) ----------
// ranges: [0,4096) W1 (K=256,N=128,NF=8); [4096,6144) W2 (K=128,N=128,NF=8);
//         [6144,7168) W3 (K=128,N=40->64,NF=4)
__global__ __launch_bounds__(256) void pack_all_kernel(const float* __restrict__ W1,
                                                       const float* __restrict__ W2,
                                                       const float* __restrict__ W3,
                                                       ushort* __restrict__ Wp1,
                                                       ushort* __restrict__ Wp2,
                                                       ushort* __restrict__ Wp3) {
  const int idx = blockIdx.x * blockDim.x + threadIdx.x;
  const float* W;
  ushort* Wp;
  int N, NF, rel;
  if (idx < 4096)      { W = W1; Wp = Wp1; N = 128; NF = 8; rel = idx; }
  else if (idx < 6144) { W = W2; Wp = Wp2; N = 128; NF = 8; rel = idx - 4096; }
  else if (idx < 7168) { W = W3; Wp = Wp3; N = 40;  NF = 4; rel = idx - 6144; }
  else return;
  const int lane = rel & 63;
  const int nf   = (rel >> 6) % NF;
  const int g    = rel / (64 * NF);
  const int n    = nf * 16 + (lane & 15);
  const int kb   = g * 32 + (lane >> 4) * 8;
  ushort v[8];
#pragma unroll
  for (int j = 0; j < 8; ++j) {
    const float f = (n < N) ? W[(size_t)(kb + j) * N + n] : 0.f;
    v[j] = f2bf(f);
  }
  *(short8*)&Wp[((size_t)(g * NF + nf) * 64 + lane) * 8] = *(short8*)v;
}

// ---------------- MFMA GEMM: C[M,Npad] = A[M,K] @ W[K,Npad], bf16 out ----------------
template <int NF, bool AF32>
__global__ __launch_bounds__(256) void mfma_gemm_kernel(const void* __restrict__ Av,
                                                        const ushort* __restrict__ Wp,
                                                        ushort* __restrict__ C,
                                                        int M, int N, int K) {
  __shared__ ushort Atile[64 * 64];
  const int tid  = threadIdx.x;
  const int lane = tid & 63;
  const int wave = tid >> 6;
  const int brow = blockIdx.x * 64;

  f32x4 acc[NF];
#pragma unroll
  for (int nf = 0; nf < NF; ++nf) acc[nf] = (f32x4){0.f, 0.f, 0.f, 0.f};

  const int arow = wave * 16 + (lane & 15);
  const int ahi  = lane >> 4;
  const int row0 = tid >> 3;
  const int kc0  = tid & 7;

  for (int k0 = 0; k0 < K; k0 += 64) {
    if (k0) __syncthreads();
#pragma unroll
    for (int c = 0; c < 2; ++c) {
      const int row = row0 + c * 32;
      const int gr  = brow + row;
      short8 v = (short8){0, 0, 0, 0, 0, 0, 0, 0};
      if (gr < M) {
        if constexpr (AF32) {
          const float* A = (const float*)Av + (size_t)gr * K + k0 + kc0 * 8;
          const float4 f0 = *(const float4*)A;
          const float4 f1 = *(const float4*)(A + 4);
          v[0] = (short)f2bf(f0.x); v[1] = (short)f2bf(f0.y);
          v[2] = (short)f2bf(f0.z); v[3] = (short)f2bf(f0.w);
          v[4] = (short)f2bf(f1.x); v[5] = (short)f2bf(f1.y);
          v[6] = (short)f2bf(f1.z); v[7] = (short)f2bf(f1.w);
        } else {
          v = *(const short8*)((const ushort*)Av + (size_t)gr * K + k0 + kc0 * 8);
        }
      }
      *(short8*)&Atile[row * 64 + ((kc0 ^ (row & 7)) * 8)] = v;
    }
    __syncthreads();

    const int gbase = (k0 >> 5) * NF;
#pragma unroll
    for (int kk = 0; kk < 2; ++kk) {
      const int kc = kk * 4 + ahi;
      const short8 a =
          *(const short8*)&Atile[arow * 64 + ((kc ^ (arow & 7)) * 8)];
      const ushort* wp = Wp + ((size_t)(gbase + kk * NF) * 64 + lane) * 8;
#pragma unroll
      for (int nf = 0; nf < NF; ++nf) {
        const short8 b = *(const short8*)(wp + (size_t)nf * 64 * 8);
        acc[nf] = __builtin_amdgcn_mfma_f32_16x16x32_bf16(a, b, acc[nf], 0, 0, 0);
      }
    }
  }

  const int crow0 = brow + wave * 16 + (lane >> 4) * 4;
  const int ccol  = lane & 15;
#pragma unroll
  for (int nf = 0; nf < NF; ++nf) {
    const int col = nf * 16 + ccol;
#pragma unroll
    for (int r = 0; r < 4; ++r) {
      const int row = crow0 + r;
      if (row < M) C[(size_t)row * N + col] = f2bf(acc[nf][r]);
    }
  }
}

// ---------------- Aggregation (128-wide): 4 edge-groups x 16 lanes x 8 feats ----------
template <bool BIAS_RELU>
__global__ __launch_bounds__(256) void agg4_kernel(const ushort* __restrict__ h,
                                                   const int* __restrict__ offsets,
                                                   const uint32_t* __restrict__ epk,
                                                   const float* __restrict__ dinv,
                                                   const float* __restrict__ bias,
                                                   ushort* __restrict__ out, int n) {
  const int wave = threadIdx.x >> 6;
  const int lane = threadIdx.x & 63;
  const int node = blockIdx.x * 4 + wave;
  if (node >= n) return;
  const int eg = lane >> 4;
  const int f0 = (lane & 15) * 8;

  float acc[8];
#pragma unroll
  for (int j = 0; j < 8; ++j) acc[j] = 0.f;

  const int start = offsets[node];
  const int end   = offsets[node + 1];
  for (int eb = start; eb < end; eb += 8) {
    const int e0 = eb + eg;
    const int e1 = e0 + 4;
    if (e0 < end) {
      const uint32_t p0 = epk[e0];
      const float    w0 = bf2f((ushort)(p0 >> 16));
      const short8   hv0 = *(const short8*)&h[(size_t)(p0 & 0xFFFF) * 128 + f0];
      if (e1 < end) {
        const uint32_t p1 = epk[e1];
        const float    w1 = bf2f((ushort)(p1 >> 16));
        const short8   hv1 = *(const short8*)&h[(size_t)(p1 & 0xFFFF) * 128 + f0];
#pragma unroll
        for (int j = 0; j < 8; ++j) {
          acc[j] = fmaf(bf2f((ushort)hv0[j]), w0, acc[j]);
          acc[j] = fmaf(bf2f((ushort)hv1[j]), w1, acc[j]);
        }
      } else {
#pragma unroll
        for (int j = 0; j < 8; ++j) acc[j] = fmaf(bf2f((ushort)hv0[j]), w0, acc[j]);
      }
    }
  }
#pragma unroll
  for (int j = 0; j < 8; ++j) {
    acc[j] += __shfl_xor(acc[j], 16, 64);
    acc[j] += __shfl_xor(acc[j], 32, 64);
  }
  if (eg == 0) {
    const float di  = dinv[node];
    const float di2 = di * di;
    const short8 hs = *(const short8*)&h[(size_t)node * 128 + f0];
    ushort o[8];
#pragma unroll
    for (int j = 0; j < 8; ++j) {
      float a = fmaf(bf2f((ushort)hs[j]), di2, acc[j]);
      if (BIAS_RELU) a = fmaxf(a + bias[f0 + j], 0.f);
      o[j] = f2bf(a);
    }
    *(short8*)&out[(size_t)node * 128 + f0] = *(short8*)o;
  }
}

// ---------------- Final agg over 64-padded bf16 logits + bias + log_softmax -------
__global__ __launch_bounds__(256) void agg40_lsm_kernel(const ushort* __restrict__ h,
                                                        const int* __restrict__ offsets,
                                                        const uint32_t* __restrict__ epk,
                                                        const float* __restrict__ dinv,
                                                        const float* __restrict__ bias,
                                                        float* __restrict__ out, int n) {
  const int wave = threadIdx.x >> 6;
  const int lane = threadIdx.x & 63;
  const int node = blockIdx.x * 4 + wave;
  if (node >= n) return;
  const int eg  = lane >> 4;
  const int l15 = lane & 15;
  const int f0  = l15 * 4;  // cols f0..f0+3 of 64 (only 0..39 meaningful)

  float acc[4] = {0.f, 0.f, 0.f, 0.f};
  const int start = offsets[node];
  const int end   = offsets[node + 1];
  for (int eb = start; eb < end; eb += 8) {
    const int e0 = eb + eg;
    const int e1 = e0 + 4;
    if (e0 < end) {
      const uint32_t p0 = epk[e0];
      const float    w0 = bf2f((ushort)(p0 >> 16));
      const short4v  hv0 = *(const short4v*)&h[(size_t)(p0 & 0xFFFF) * 64 + f0];
      if (e1 < end) {
        const uint32_t p1 = epk[e1];
        const float    w1 = bf2f((ushort)(p1 >> 16));
        const short4v  hv1 = *(const short4v*)&h[(size_t)(p1 & 0xFFFF) * 64 + f0];
#pragma unroll
        for (int j = 0; j < 4; ++j) {
          acc[j] = fmaf(bf2f((ushort)hv0[j]), w0, acc[j]);
          acc[j] = fmaf(bf2f((ushort)hv1[j]), w1, acc[j]);
        }
      } else {
#pragma unroll
        for (int j = 0; j < 4; ++j) acc[j] = fmaf(bf2f((ushort)hv0[j]), w0, acc[j]);
      }
    }
  }
#pragma unroll
  for (int j = 0; j < 4; ++j) {
    acc[j] += __shfl_xor(acc[j], 16, 64);
    acc[j] += __shfl_xor(acc[j], 32, 64);
  }
  if (eg == 0) {
    const bool valid = l15 < 10;  // cols 0..39 (40 = 10 lanes x 4)
    const float di  = dinv[node];
    const float di2 = di * di;
    const short4v hs = *(const short4v*)&h[(size_t)node * 64 + f0];
    float v[4];
    if (valid) {
#pragma unroll
      for (int j = 0; j < 4; ++j)
        v[j] = fmaf(bf2f((ushort)hs[j]), di2, acc[j]) + bias[f0 + j];
    } else {
#pragma unroll
      for (int j = 0; j < 4; ++j) v[j] = -INFINITY;
    }
    float m = fmaxf(fmaxf(v[0], v[1]), fmaxf(v[2], v[3]));
#pragma unroll
    for (int o = 8; o >= 1; o >>= 1) m = fmaxf(m, __shfl_xor(m, o, 64));
    float s = valid ? (expf(v[0] - m) + expf(v[1] - m) + expf(v[2] - m) + expf(v[3] - m)) : 0.f;
#pragma unroll
    for (int o = 8; o >= 1; o >>= 1) s += __shfl_xor(s, o, 64);
    const float mls = m + logf(s);
    if (valid) {
      float4 o4 = make_float4(v[0] - mls, v[1] - mls, v[2] - mls, v[3] - mls);
      *(float4*)&out[(size_t)node * 40 + f0] = o4;
    }
  }
}

extern "C" void kernel_launch(void* const* d_in, const int* in_sizes, int n_in,
                              void* d_out, int out_size, void* d_ws, size_t ws_size,
                              hipStream_t stream) {
  const float* x  = (const float*)d_in[0];
  const int*   ei = (const int*)d_in[1];
  const float* W1 = (const float*)d_in[2];
  const float* b1 = (const float*)d_in[3];
  const float* W2 = (const float*)d_in[4];
  const float* b2 = (const float*)d_in[5];
  const float* W3 = (const float*)d_in[6];
  const float* b3 = (const float*)d_in[7];

  const int h1   = in_sizes[3];        // 128
  const int h2   = in_sizes[5];        // 128
  const int ncls = in_sizes[7];        // 40
  const int fin  = in_sizes[2] / h1;   // 256
  const int n    = in_sizes[0] / fin;  // 50000 (packing requires n <= 65536)
  const int E    = in_sizes[1] / 2;    // 800000

  const int* src = ei;
  const int* dst = ei + E;

  char* p = (char*)d_ws;
  auto alloc = [&](size_t bytes) {
    char* r = p;
    p += (bytes + 255) & ~size_t(255);
    return r;
  };
  const int nbuck = (n + 255) >> 8;        // 196
  const int ebw   = (E + EPB - 1) / EPB;   // 196

  float*    dinv   = (float*)alloc((size_t)n * 4);
  int*      offs   = (int*)alloc((size_t)(n + 1) * 4);
  int*      bcount = (int*)alloc(256 * 4);
  int*      boffs  = (int*)alloc(257 * 4);
  int*      bcur   = (int*)alloc(256 * 4);
  int*      wgh    = (int*)alloc((size_t)ebw * 256 * 4);  // per-wg bucket hist
  uint32_t* staged = (uint32_t*)alloc((size_t)E * 4);
  uint32_t* epk    = (uint32_t*)alloc((size_t)E * 4);
  ushort*   bufA   = (ushort*)alloc((size_t)n * h1 * 2);  // G1/G2 out
  ushort*   bufB   = (ushort*)alloc((size_t)n * h1 * 2);  // a1/a2 out
  ushort*   hs     = (ushort*)alloc((size_t)n * 64 * 2);  // G3 out (padded logits)
  ushort*   Wp1    = (ushort*)alloc((size_t)(fin / 32) * 8 * 64 * 8 * 2);
  ushort*   Wp2    = (ushort*)alloc((size_t)(h1 / 32) * 8 * 64 * 8 * 2);
  ushort*   Wp3    = (ushort*)alloc((size_t)(h2 / 32) * 4 * 64 * 8 * 2);

  // --- CSR build: 2-level bucket sort ---
  hipMemsetAsync(bcount, 0, 256 * 4, stream);
  bucket_hist_kernel<<<ebw, 256, 0, stream>>>(dst, bcount, wgh, E);
  bucket_scan_kernel<<<1, 256, 0, stream>>>(bcount, boffs, bcur, offs, nbuck, n);
  bucket_scatter_kernel<<<ebw, 256, 0, stream>>>(src, dst, wgh, bcur, staged, E, nbuck);
  bucket_csr_kernel<<<nbuck, 256, 0, stream>>>(staged, boffs, offs, dinv, n);
  bucket_fill_kernel<<<nbuck, 256, 0, stream>>>(staged, boffs, offs, dinv, epk, n);

  // --- pack all weights in one launch (fragment order, bf16) ---
  pack_all_kernel<<<28, 256, 0, stream>>>(W1, W2, W3, Wp1, Wp2, Wp3);

  const int gblocks = (n + 63) / 64;
  const int ablocks = (n + 3) / 4;

  // --- layer 1 ---
  mfma_gemm_kernel<8, true><<<gblocks, 256, 0, stream>>>(x, Wp1, bufA, n, h1, fin);
  agg4_kernel<true><<<ablocks, 256, 0, stream>>>(bufA, offs, epk, dinv, b1, bufB, n);
  // --- layer 2 ---
  mfma_gemm_kernel<8, false><<<gblocks, 256, 0, stream>>>(bufB, Wp2, bufA, n, h2, h1);
  agg4_kernel<true><<<ablocks, 256, 0, stream>>>(bufA, offs, epk, dinv, b2, bufB, n);
  // --- layer 3: GEMM first (40 cols padded to 64), then agg + bias + lsm ---
  mfma_gemm_kernel<4, false><<<gblocks, 256, 0, stream>>>(bufB, Wp3, hs, n, 64, h2);
  agg40_lsm_kernel<<<ablocks, 256, 0, stream>>>(hs, offs, epk, dinv, b3,
                                                (float*)d_out, n);
}